// Round 2
// baseline (197.892 us; speedup 1.0000x reference)
//
#include <hip/hip_runtime.h>

#define BT    16
#define NN    10242
#define CC    64
#define KK    9
#define NBR_  7
#define OO    64
#define CK    576
#define MT    64            // rows (nodes) per block -> LDS 74.75KB -> 2 blocks/CU
#define RS    584           // LDS itp row stride in bf16 (16B-aligned, bank-spread)
#define KT    18            // K tiles of 32

using frag  = __attribute__((ext_vector_type(8))) short;   // 8 bf16 (4 VGPRs)
using f32x4 = __attribute__((ext_vector_type(4))) float;

static __device__ __forceinline__ unsigned short f2bf(float f) {
    union { float f; unsigned u; } v; v.f = f;
    unsigned r = v.u + 0x7fffu + ((v.u >> 16) & 1u);   // RNE
    return (unsigned short)(r >> 16);
}

// q-permutation shared by producer and weight pack:
//   k in [0,8): q = (k>>2)*256 + c*4 + (k&3);  k==8: q = 512 + c
// wb[((t*4+ct)*64+lane)*8+j] = bf16(w[o][c][k]), q=t*32+(lane>>4)*8+j, o=ct*16+(lane&15)
__global__ void pack_w_kernel(const float* __restrict__ w, unsigned short* __restrict__ wb) {
    int i = blockIdx.x * blockDim.x + threadIdx.x;
    if (i >= KT * 4 * 64 * 8) return;
    int j  = i & 7;
    int l  = (i >> 3) & 63;
    int ct = (i >> 9) & 3;
    int t  = i >> 11;
    int q  = t * 32 + (l >> 4) * 8 + j;
    int o  = ct * 16 + (l & 15);
    int c, k;
    if (q < 512) { c = (q & 255) >> 2; k = (q >> 8) * 4 + (q & 3); }
    else         { c = q - 512;        k = 8; }
    wb[i] = f2bf(w[(o * CC + c) * KK + k]);
}

__global__ __launch_bounds__(256, 2) void sphere_conv_kernel(
    const float* __restrict__ x,      // (BT, N, C)
    const int*   __restrict__ index,  // (N, NBR)
    const float* __restrict__ m,      // (N, NBR, K)
    const unsigned short* __restrict__ wb,  // packed B frags (bf16 bits)
    const float* __restrict__ bias,   // (O,)
    float*       __restrict__ out)    // (BT, N, O)
{
    __shared__ unsigned short itp_s[MT * RS];   // 74752 B -> 2 blocks/CU

    const int tid  = threadIdx.x;
    const int nt   = blockIdx.x;                // n-tile fastest
    const int bt   = blockIdx.y;
    const int n0   = nt * MT;
    const int w    = tid >> 6;
    const int lane = tid & 63;

    // ---- B fragments: hoist ALL 18 into VGPRs at kernel start --------------
    // 72 VGPRs; loads issue here and latency hides under the producer phase.
    // Reused across 4 node-subtiles -> wb L2 traffic /4 vs per-tile streaming.
    const frag* wbf = (const frag*)wb;
    frag bfr[KT];
    #pragma unroll
    for (int t = 0; t < KT; ++t) bfr[t] = wbf[(t * 4 + w) * 64 + lane];

    // ---------------- Producer: 16 rows/wave, lane = channel -----------------
    // Chunks of 4 rows: 28 gathers issued before any FMA; launch_bounds(256,2)
    // gives the allocator 256 VGPRs so the loads actually stay in flight.
    {
        const float* xbt = x + (size_t)bt * NN * CC;
        #pragma unroll
        for (int rc = 0; rc < 4; ++rc) {
            int nu[4];
            #pragma unroll
            for (int r = 0; r < 4; ++r) {
                const int n = n0 + w * 16 + rc * 4 + r;
                // clamp (reads stay in-bounds; junk rows never stored) + force
                // wave-uniform so index/m go through scalar loads (K$/L2)
                nu[r] = __builtin_amdgcn_readfirstlane(n < NN ? n : (NN - 1));
            }

            float xv[4][NBR_];
            #pragma unroll
            for (int r = 0; r < 4; ++r) {
                const int* ip = index + nu[r] * NBR_;          // SGPR base -> s_load
                #pragma unroll
                for (int j = 0; j < NBR_; ++j)
                    xv[r][j] = xbt[(size_t)ip[j] * CC + lane]; // coalesced 256B gather
            }

            #pragma unroll
            for (int r = 0; r < 4; ++r) {
                const int ns = w * 16 + rc * 4 + r;
                const float* mp = m + nu[r] * (NBR_ * KK);     // SGPR base -> s_load
                float acc[KK];
                #pragma unroll
                for (int k = 0; k < KK; ++k) acc[k] = 0.f;
                #pragma unroll
                for (int j = 0; j < NBR_; ++j)
                    #pragma unroll
                    for (int k = 0; k < KK; ++k)
                        acc[k] = fmaf(xv[r][j], mp[j * KK + k], acc[k]);

                unsigned short h[KK];
                #pragma unroll
                for (int k = 0; k < KK; ++k) h[k] = f2bf(acc[k]);
                uint2 q0, q1;
                q0.x = (unsigned)h[0] | ((unsigned)h[1] << 16);
                q0.y = (unsigned)h[2] | ((unsigned)h[3] << 16);
                q1.x = (unsigned)h[4] | ((unsigned)h[5] << 16);
                q1.y = (unsigned)h[6] | ((unsigned)h[7] << 16);
                unsigned short* row = &itp_s[ns * RS];
                *(uint2*)(&row[lane * 4])       = q0;          // 8B, conflict-free
                *(uint2*)(&row[256 + lane * 4]) = q1;
                row[512 + lane] = h[8];
            }
        }
    }
    __syncthreads();

    // ------------- Consumer: wave = 16 o-cols x (4 x 16-node subtiles) ------
    const int am   = lane & 15;
    const int half = lane >> 4;
    const int o    = w * 16 + am;
    const float bo = bias[o];
    const size_t obase = (size_t)bt * NN * OO;

    #pragma unroll
    for (int g = 0; g < 4; ++g) {
        const unsigned short* arow = &itp_s[(g * 16 + am) * RS + half * 8];
        f32x4 acc = (f32x4){0.f, 0.f, 0.f, 0.f};
        #pragma unroll
        for (int t = 0; t < KT; ++t) {
            const frag a = *(const frag*)(arow + t * 32);   // ds_read_b128
            acc = __builtin_amdgcn_mfma_f32_16x16x32_bf16(a, bfr[t], acc, 0, 0, 0);
        }
        // D layout: col = lane&15, row = (lane>>4)*4 + i
        #pragma unroll
        for (int i = 0; i < 4; ++i) {
            const int n = n0 + g * 16 + half * 4 + i;
            if (n < NN) out[obase + (size_t)n * OO + o] = acc[i] + bo;
        }
    }
}

extern "C" void kernel_launch(void* const* d_in, const int* in_sizes, int n_in,
                              void* d_out, int out_size, void* d_ws, size_t ws_size,
                              hipStream_t stream) {
    const float* x      = (const float*)d_in[0];
    const int*   index  = (const int*)  d_in[1];
    const float* m      = (const float*)d_in[2];
    const float* conv_w = (const float*)d_in[3];
    const float* conv_b = (const float*)d_in[4];
    float* out = (float*)d_out;
    unsigned short* wb = (unsigned short*)d_ws;   // 73728 B

    {   // pack weights into MFMA B-fragment order
        const int total = KT * 4 * 64 * 8;
        pack_w_kernel<<<(total + 255) / 256, 256, 0, stream>>>(conv_w, wb);
    }
    {   // fused gather + interp + MFMA conv
        dim3 grid((NN + MT - 1) / MT, BT);        // 161 x 16
        sphere_conv_kernel<<<grid, 256, 0, stream>>>(x, index, m, wb, conv_b, out);
    }
}

// Round 4
// 169.789 us; speedup vs baseline: 1.1655x; 1.1655x over previous
//
#include <hip/hip_runtime.h>

#define BT     16
#define NN     10242
#define CC     64
#define KK     9
#define NBR_   7
#define OO     64
#define CK     576
#define MT     16            // rows (nodes) per tile
#define RS     584           // LDS itp row stride in bf16 (16B-aligned, bank-spread)
#define KT     18            // K tiles of 32
#define NTILES 641           // ceil(NN/MT)
#define NGRP   321           // ceil(NTILES/2) tile-pairs per bt

using frag  = __attribute__((ext_vector_type(8))) short;   // 8 bf16 (4 VGPRs)
using f32x4 = __attribute__((ext_vector_type(4))) float;

static __device__ __forceinline__ unsigned short f2bf(float f) {
    union { float f; unsigned u; } v; v.f = f;
    unsigned r = v.u + 0x7fffu + ((v.u >> 16) & 1u);   // RNE
    return (unsigned short)(r >> 16);
}

// q-permutation shared by producer and weight pack:
//   k in [0,8): q = (k>>2)*256 + c*4 + (k&3);  k==8: q = 512 + c
// wb[((t*4+ct)*64+lane)*8+j] = bf16(w[o][c][k]), q=t*32+(lane>>4)*8+j, o=ct*16+(lane&15)
__global__ void pack_w_kernel(const float* __restrict__ w, unsigned short* __restrict__ wb) {
    int i = blockIdx.x * blockDim.x + threadIdx.x;
    if (i >= KT * 4 * 64 * 8) return;
    int j  = i & 7;
    int l  = (i >> 3) & 63;
    int ct = (i >> 9) & 3;
    int t  = i >> 11;
    int q  = t * 32 + (l >> 4) * 8 + j;
    int o  = ct * 16 + (l & 15);
    int c, k;
    if (q < 512) { c = (q & 255) >> 2; k = (q >> 8) * 4 + (q & 3); }
    else         { c = q - 512;        k = 8; }
    wb[i] = f2bf(w[(o * CC + c) * KK + k]);
}

// Producer: one 16-node tile -> LDS buf. 4 waves x 4 rows, lane = channel.
// All 28 gathers issued before any FMA.
static __device__ __forceinline__ void produce_tile(
    const float* __restrict__ xbt, const int* __restrict__ index,
    const float* __restrict__ m, unsigned short* __restrict__ buf,
    int n0, int w, int lane)
{
    int nu[4];
    #pragma unroll
    for (int r = 0; r < 4; ++r) {
        const int n = n0 + w * 4 + r;
        // clamp (reads stay in-bounds; junk rows never stored) + wave-uniform
        // so index/m go through scalar loads (K$/L2)
        nu[r] = __builtin_amdgcn_readfirstlane(n < NN ? n : (NN - 1));
    }
    float xv[4][NBR_];
    #pragma unroll
    for (int r = 0; r < 4; ++r) {
        const int* ip = index + nu[r] * NBR_;              // SGPR base -> s_load
        #pragma unroll
        for (int j = 0; j < NBR_; ++j)
            xv[r][j] = xbt[(size_t)ip[j] * CC + lane];     // coalesced 256B gather
    }
    #pragma unroll
    for (int r = 0; r < 4; ++r) {
        const int ns = w * 4 + r;
        const float* mp = m + nu[r] * (NBR_ * KK);         // SGPR base -> s_load
        float acc[KK];
        #pragma unroll
        for (int k = 0; k < KK; ++k) acc[k] = 0.f;
        #pragma unroll
        for (int j = 0; j < NBR_; ++j)
            #pragma unroll
            for (int k = 0; k < KK; ++k)
                acc[k] = fmaf(xv[r][j], mp[j * KK + k], acc[k]);

        unsigned short h[KK];
        #pragma unroll
        for (int k = 0; k < KK; ++k) h[k] = f2bf(acc[k]);
        uint2 q0, q1;
        q0.x = (unsigned)h[0] | ((unsigned)h[1] << 16);
        q0.y = (unsigned)h[2] | ((unsigned)h[3] << 16);
        q1.x = (unsigned)h[4] | ((unsigned)h[5] << 16);
        q1.y = (unsigned)h[6] | ((unsigned)h[7] << 16);
        unsigned short* row = &buf[ns * RS];
        *(uint2*)(&row[lane * 4])       = q0;              // 8B, conflict-free
        *(uint2*)(&row[256 + lane * 4]) = q1;
        row[512 + lane] = h[8];
    }
}

// Consumer: wave = 16 nodes x 16 o-cols using register-resident B frags.
static __device__ __forceinline__ void consume_tile(
    const unsigned short* __restrict__ buf, const frag* __restrict__ bfr,
    float* __restrict__ out, size_t obase, int n0, int w, int lane, float bo)
{
    const int am   = lane & 15;
    const int half = lane >> 4;
    const int o    = w * 16 + am;
    const unsigned short* arow = &buf[am * RS + half * 8];
    f32x4 acc = (f32x4){0.f, 0.f, 0.f, 0.f};
    #pragma unroll
    for (int t = 0; t < KT; ++t) {
        const frag a = *(const frag*)(arow + t * 32);       // ds_read_b128
        acc = __builtin_amdgcn_mfma_f32_16x16x32_bf16(a, bfr[t], acc, 0, 0, 0);
    }
    // D layout: col = lane&15, row = (lane>>4)*4 + i
    #pragma unroll
    for (int i = 0; i < 4; ++i) {
        const int n = n0 + half * 4 + i;
        if (n < NN) out[obase + (size_t)n * OO + o] = acc[i] + bo;
    }
}

__global__ __launch_bounds__(256, 4) void sphere_conv_kernel(
    const float* __restrict__ x,      // (BT, N, C)
    const int*   __restrict__ index,  // (N, NBR)
    const float* __restrict__ m,      // (N, NBR, K)
    const unsigned short* __restrict__ wb,  // packed B frags (bf16 bits)
    const float* __restrict__ bias,   // (O,)
    float*       __restrict__ out)    // (BT, N, O)
{
    __shared__ unsigned short itp_s[2][MT * RS];   // 2 x 18688B = 37376B -> 4 blk/CU

    const int tid  = threadIdx.x;
    const int w    = tid >> 6;
    const int lane = tid & 63;

    // ---- XCD-ownership swizzle: XCD c owns bt {2c, 2c+1}, sweeps nt in order.
    // blockIdx.x -> XCD is round-robin (%8); slot increments within an XCD, so
    // each XCD streams one 2.62MB x-slice at a time -> gathers hit its L2.
    const int bid  = blockIdx.x;               // [0, 8*2*NGRP)
    const int xcd  = bid & 7;
    const int slot = bid >> 3;                 // [0, 2*NGRP)
    const int btl  = slot / NGRP;              // 0 or 1
    const int g    = slot - btl * NGRP;        // [0, NGRP)
    const int bt   = xcd * 2 + btl;
    const int n00  = (g * 2) * MT;             // tile pair
    const int n01  = n00 + MT;
    const bool has1 = (g * 2 + 1) < NTILES;    // block-uniform

    const float* xbt = x + (size_t)bt * NN * CC;
    const size_t obase = (size_t)bt * NN * OO;

    // ---- B fragments: 18 frags (72 VGPRs) per wave, loaded ONCE per block,
    // reused for both tiles. Loads issue here; latency hides under producer.
    const frag* wbf = (const frag*)wb;
    frag bfr[KT];
    #pragma unroll
    for (int t = 0; t < KT; ++t) bfr[t] = wbf[(t * 4 + w) * 64 + lane];

    const float bo = bias[w * 16 + (lane & 15)];

    produce_tile(xbt, index, m, itp_s[0], n00, w, lane);
    __syncthreads();

    // Produce tile 1 BEFORE consuming tile 0: t1's gathers issue first and
    // their latency hides under t0's MFMA + store work (no barrier between:
    // buf1 writes vs buf0 reads are disjoint).
    if (has1) produce_tile(xbt, index, m, itp_s[1], n01, w, lane);
    consume_tile(itp_s[0], bfr, out, obase, n00, w, lane, bo);
    if (has1) {
        __syncthreads();
        consume_tile(itp_s[1], bfr, out, obase, n01, w, lane, bo);
    }
}

extern "C" void kernel_launch(void* const* d_in, const int* in_sizes, int n_in,
                              void* d_out, int out_size, void* d_ws, size_t ws_size,
                              hipStream_t stream) {
    const float* x      = (const float*)d_in[0];
    const int*   index  = (const int*)  d_in[1];
    const float* m      = (const float*)d_in[2];
    const float* conv_w = (const float*)d_in[3];
    const float* conv_b = (const float*)d_in[4];
    float* out = (float*)d_out;
    unsigned short* wb = (unsigned short*)d_ws;   // 73728 B

    {   // pack weights into MFMA B-fragment order
        const int total = KT * 4 * 64 * 8;
        pack_w_kernel<<<(total + 255) / 256, 256, 0, stream>>>(conv_w, wb);
    }
    {   // fused gather + interp + MFMA conv; 8 XCDs x 2 bt x 321 tile-pairs
        dim3 grid(8 * 2 * NGRP);                  // 5136 blocks
        sphere_conv_kernel<<<grid, 256, 0, stream>>>(x, index, m, wb, conv_b, out);
    }
}

// Round 6
// 145.449 us; speedup vs baseline: 1.3606x; 1.1673x over previous
//
#include <hip/hip_runtime.h>

#define BT    16
#define NN    10242
#define CC    64
#define KK    9
#define NBR_  7
#define OO    64
#define CK    576
#define MT    16            // rows (nodes) per block  -> LDS 18.7KB -> 8 blocks/CU
#define RS    584           // LDS itp row stride in bf16 (16B-aligned)
#define KT    18            // K tiles of 32

using frag  = __attribute__((ext_vector_type(8))) short;   // 8 bf16 (4 VGPRs)
using f32x4 = __attribute__((ext_vector_type(4))) float;

static __device__ __forceinline__ unsigned short f2bf(float f) {
    union { float f; unsigned u; } v; v.f = f;
    unsigned r = v.u + 0x7fffu + ((v.u >> 16) & 1u);   // RNE
    return (unsigned short)(r >> 16);
}

// packed pair via v_cvt_pk_bf16_f32 (native RNE pack — bit-identical to f2bf).
// No builtin exists on gfx950; non-volatile asm stays scheduler-reorderable.
static __device__ __forceinline__ unsigned pk2(float a, float b) {
    unsigned r;
    asm("v_cvt_pk_bf16_f32 %0, %1, %2" : "=v"(r) : "v"(a), "v"(b));
    return r;
}

// q-permutation shared by producer and weight pack:
//   k in [0,8): q = (k>>2)*256 + c*4 + (k&3);  k==8: q = 512 + c
// wb[((t*4+ct)*64+lane)*8+j] = bf16(w[o][c][k]), q=t*32+(lane>>4)*8+j, o=ct*16+(lane&15)
__global__ void pack_w_kernel(const float* __restrict__ w, unsigned short* __restrict__ wb) {
    int i = blockIdx.x * blockDim.x + threadIdx.x;
    if (i >= KT * 4 * 64 * 8) return;
    int j  = i & 7;
    int l  = (i >> 3) & 63;
    int ct = (i >> 9) & 3;
    int t  = i >> 11;
    int q  = t * 32 + (l >> 4) * 8 + j;
    int o  = ct * 16 + (l & 15);
    int c, k;
    if (q < 512) { c = (q & 255) >> 2; k = (q >> 8) * 4 + (q & 3); }
    else         { c = q - 512;        k = 8; }
    wb[i] = f2bf(w[(o * CC + c) * KK + k]);
}

__global__ __launch_bounds__(256, 8) void sphere_conv_kernel(
    const float* __restrict__ x,      // (BT, N, C)
    const int*   __restrict__ index,  // (N, NBR)
    const float* __restrict__ m,      // (N, NBR, K)
    const unsigned short* __restrict__ wb,  // packed B frags (bf16 bits)
    const float* __restrict__ bias,   // (O,)
    float*       __restrict__ out)    // (BT, N, O)
{
    __shared__ unsigned short itp_s[MT * RS];   // 18688 B -> 8 blocks/CU

    const int tid  = threadIdx.x;
    const int nt   = blockIdx.x;                // n-tile fastest (R1 layout)
    const int bt   = blockIdx.y;
    const int n0   = nt * MT;
    const int w    = tid >> 6;
    const int lane = tid & 63;

    // ---------------- Producer: 4 rows/wave, lane = channel ------------------
    {
        const float* xbt = x + (size_t)bt * NN * CC;

        int nu[4];
        #pragma unroll
        for (int r = 0; r < 4; ++r) {
            const int n = n0 + w * 4 + r;
            // clamp (reads stay in-bounds; junk rows never stored) + wave-uniform
            // so index/m go through scalar loads (K$/L2)
            nu[r] = __builtin_amdgcn_readfirstlane(n < NN ? n : (NN - 1));
        }

        // Issue ALL 28 gathers, then a scheduling fence: the compiler cannot
        // sink loads below it, so all 28 stay in flight (28 live VGPRs) and
        // one wave eats ONE gather round-trip instead of four.
        float xv[4][NBR_];
        #pragma unroll
        for (int r = 0; r < 4; ++r) {
            const int* ip = index + nu[r] * NBR_;          // SGPR base -> s_load
            #pragma unroll
            for (int j = 0; j < NBR_; ++j)
                xv[r][j] = xbt[(size_t)ip[j] * CC + lane]; // coalesced 256B gather
        }
        __builtin_amdgcn_sched_barrier(0);

        #pragma unroll
        for (int r = 0; r < 4; ++r) {
            const int ns = w * 4 + r;
            const float* mp = m + nu[r] * (NBR_ * KK);     // SGPR base -> s_load
            float acc[KK];
            #pragma unroll
            for (int k = 0; k < KK; ++k) acc[k] = 0.f;
            #pragma unroll
            for (int j = 0; j < NBR_; ++j)
                #pragma unroll
                for (int k = 0; k < KK; ++k)
                    acc[k] = fmaf(xv[r][j], mp[j * KK + k], acc[k]);

            // pack 8 values with v_cvt_pk_bf16_f32 (was ~40 VALU of bit-twiddle)
            uint2 q0, q1;
            q0.x = pk2(acc[0], acc[1]);
            q0.y = pk2(acc[2], acc[3]);
            q1.x = pk2(acc[4], acc[5]);
            q1.y = pk2(acc[6], acc[7]);
            unsigned short* row = &itp_s[ns * RS];
            *(uint2*)(&row[lane * 4])       = q0;          // 8B, 2-way banks = free
            *(uint2*)(&row[256 + lane * 4]) = q1;
            row[512 + lane] = f2bf(acc[8]);
        }
    }
    __syncthreads();

    // ------------- Consumer: wave = 16 rows x 16 cols (ct = wave id) --------
    const int ct   = w;
    const int am   = lane & 15;
    const int half = lane >> 4;

    f32x4 acc = (f32x4){0.f, 0.f, 0.f, 0.f};

    const unsigned short* arow = &itp_s[am * RS + half * 8];
    const frag* wbf = (const frag*)wb;

    #pragma unroll
    for (int t = 0; t < KT; ++t) {
        const frag a = *(const frag*)(arow + t * 32);       // ds_read_b128
        const frag b = wbf[(t * 4 + ct) * 64 + lane];       // L2-hot
        acc = __builtin_amdgcn_mfma_f32_16x16x32_bf16(a, b, acc, 0, 0, 0);
    }

    // ---------------- Epilogue: bias + store ---------------------------------
    // D layout: col = lane&15, row = (lane>>4)*4 + i
    const size_t obase = (size_t)bt * NN * OO;
    {
        const int o  = ct * 16 + am;
        const float bo = bias[o];
        #pragma unroll
        for (int i = 0; i < 4; ++i) {
            const int n = n0 + half * 4 + i;
            if (n < NN) out[obase + (size_t)n * OO + o] = acc[i] + bo;
        }
    }
}

extern "C" void kernel_launch(void* const* d_in, const int* in_sizes, int n_in,
                              void* d_out, int out_size, void* d_ws, size_t ws_size,
                              hipStream_t stream) {
    const float* x      = (const float*)d_in[0];
    const int*   index  = (const int*)  d_in[1];
    const float* m      = (const float*)d_in[2];
    const float* conv_w = (const float*)d_in[3];
    const float* conv_b = (const float*)d_in[4];
    float* out = (float*)d_out;
    unsigned short* wb = (unsigned short*)d_ws;   // 73728 B

    {   // pack weights into MFMA B-fragment order
        const int total = KT * 4 * 64 * 8;
        pack_w_kernel<<<(total + 255) / 256, 256, 0, stream>>>(conv_w, wb);
    }
    {   // fused gather + interp + MFMA conv (R1 grid: n-tile fastest)
        dim3 grid((NN + MT - 1) / MT, BT);        // 641 x 16
        sphere_conv_kernel<<<grid, 256, 0, stream>>>(x, index, m, wb, conv_b, out);
    }
}